// Round 13
// baseline (141.506 us; speedup 1.0000x reference)
//
#include <hip/hip_runtime.h>
#include <hip/hip_bf16.h>
#include <hip/hip_fp16.h>

#define Bn 2048
#define Tn 128
#define Vn 256
#define Cn 32
#define Hn 128
#define En 256
#define On 256
#define Gn 384
#define BNn 32

typedef _Float16 f16;
typedef __attribute__((ext_vector_type(8))) _Float16 h8;
typedef __attribute__((ext_vector_type(4))) _Float16 h4;
typedef __attribute__((ext_vector_type(2))) _Float16 h2;
typedef __attribute__((ext_vector_type(2))) __fp16 hb2;
typedef __attribute__((ext_vector_type(4))) float f4;

#define LOG2E 1.4426950408889634f

__device__ __forceinline__ f16 hexp2(f16 x) {
  f16 r;
  asm("v_exp_f16 %0, %1" : "=v"(r) : "v"(x));
  return r;
}
__device__ __forceinline__ f16 hrcp(f16 x) {
  f16 r;
  asm("v_rcp_f16 %0, %1" : "=v"(r) : "v"(x));
  return r;
}
__device__ __forceinline__ h2 pkrtz(float a, float b) {
  return __builtin_bit_cast(h2, __builtin_amdgcn_cvt_pkrtz(a, b));
}
__device__ __forceinline__ float dot2(h2 a, h2 b, float c) {
#if __has_builtin(__builtin_amdgcn_fdot2)
  return __builtin_amdgcn_fdot2(__builtin_bit_cast(hb2, a), __builtin_bit_cast(hb2, b), c, false);
#else
  return fmaf((float)a[0], (float)b[0], fmaf((float)a[1], (float)b[1], c));
#endif
}

// ---------------- Kernel 1: packed scaled xp table (f16) ----------------
// xt[dir][v][j][4] = { -log2e*(xr+bir+bhhr), -log2e*(xz+biz+bhhz), 2log2e*(xn+bin), 0 }
__global__ void build_table_k(const float* __restrict__ emb,
                              const float* __restrict__ wf,
                              const float* __restrict__ bif,
                              const float* __restrict__ bhf,
                              const float* __restrict__ wb,
                              const float* __restrict__ bib,
                              const float* __restrict__ bhb,
                              f16* __restrict__ xt) {
  const int dir = blockIdx.x >> 8;
  const int v = blockIdx.x & 255;
  const int j = threadIdx.x;  // 128 threads
  const float* w = dir ? wb : wf;
  const float* bi = dir ? bib : bif;
  const float* bh = dir ? bhb : bhf;
  const float sc[3] = {-LOG2E, -LOG2E, 2.0f * LOG2E};
  h4 o;
  o[3] = (f16)0.f;
#pragma unroll
  for (int ga = 0; ga < 3; ++ga) {
    const int g = ga * Hn + j;
    float acc = bi[g] + (ga < 2 ? bh[g] : 0.f);
    const f4* wr = (const f4*)(w + g * Cn);
    const f4* er = (const f4*)(emb + v * Cn);
#pragma unroll
    for (int q = 0; q < 8; ++q) {
      f4 wv = wr[q], ev = er[q];
      acc = fmaf(ev.x, wv.x, acc);
      acc = fmaf(ev.y, wv.y, acc);
      acc = fmaf(ev.z, wv.z, acc);
      acc = fmaf(ev.w, wv.w, acc);
    }
    o[ga] = (f16)(acc * sc[ga]);
  }
  *(h4*)&xt[((dir * Vn + v) * Hn + j) * 4] = o;
}

// ---------------- Kernel 1b: weight f32->f16 conversion ----------------
// 112 blocks x 256 threads x 4 elems: proj_w (65536) then down_w/up_w (24576 each)
__global__ void cvt_k(const float* __restrict__ pw,
                      const float* __restrict__ dw,
                      const float* __restrict__ uw,
                      f16* __restrict__ pwh,
                      f16* __restrict__ dwh,
                      f16* __restrict__ uwh) {
  const int i = (blockIdx.x * 256 + threadIdx.x) * 4;
  if (i < 65536) {
    f4 v = *(const f4*)(pw + i);
    h4 o = {(f16)v.x, (f16)v.y, (f16)v.z, (f16)v.w};
    *(h4*)(pwh + i) = o;
  } else {
    const int k = i - 65536;
    if (k < 3 * BNn * En) {
      f4 v = *(const f4*)(dw + k);
      h4 o = {(f16)v.x, (f16)v.y, (f16)v.z, (f16)v.w};
      *(h4*)(dwh + k) = o;
      f4 u = *(const f4*)(uw + k);
      h4 p = {(f16)u.x, (f16)u.y, (f16)u.z, (f16)u.w};
      *(h4*)(uwh + k) = p;
    }
  }
}

// ---------------- Kernel 2: bidirectional GRU ----------------
// 256 blocks x 1024 threads (16 waves, 4/SIMD). Wave pair (w, w+8) duplicates the
// 12-MFMA chain for j-tile (w&7); gates row-split: half=w>>3 processes C rows
// {2*half, 2*half+1} of each lg group. h fragment-major XOR-32 swizzled dbuf.
// xp/tokens prefetched one step ahead; barrier drains lgkmcnt only.
__launch_bounds__(1024, 1)
__global__ void gru_k(const int* __restrict__ tokens,
                      const float* __restrict__ whhf,
                      const float* __restrict__ bhhf,
                      const float* __restrict__ whhb,
                      const float* __restrict__ bhhb,
                      const f16* __restrict__ xt,
                      float* __restrict__ feat) {
  const int dir = blockIdx.x & 1;
  const int b0 = (blockIdx.x >> 1) * 16;
  const int tid = threadIdx.x;
  const int wave = tid >> 6;       // 0..15
  const int hf = wave >> 3;        // row-half: 0 -> rows {0,1}, 1 -> rows {2,3}
  const int wv = wave & 7;         // j-tile
  const int ln = tid & 63;
  const int lr = ln & 15;
  const int lg = ln >> 4;
  const int j = wv * 16 + lr;

  __shared__ f16 hfrag[2 * 2048];  // 2 x 4KB, XOR-32 swizzled
  __shared__ int tokT[Tn * 16];    // [t][s], direction-adjusted, value = tok<<10

  for (int i = tid; i < Tn * 16; i += 1024) {
    const int t = i >> 4, s = i & 15;
    tokT[i] = tokens[(b0 + s) * Tn + (dir ? (Tn - 1 - t) : t)] << 10;
  }
  for (int i = tid; i < 2 * 2048; i += 1024) hfrag[i] = (f16)0.f;

  const float* whh = dir ? whhb : whhf;
  const float* bhh = dir ? bhhb : bhhf;
  const char* tab = (const char*)(xt + dir * (Vn * Hn * 4));

  // register-resident gate-scaled B frags (identical in both halves of a pair)
  const float gsc[3] = {-LOG2E, -LOG2E, 2.0f * LOG2E};
  h8 Bf[3][4];
#pragma unroll
  for (int ga = 0; ga < 3; ++ga) {
    const float* wr = whh + (ga * Hn + j) * Hn + lg * 8;
#pragma unroll
    for (int kk = 0; kk < 4; ++kk) {
      h8 b;
#pragma unroll
      for (int i = 0; i < 8; ++i) b[i] = (f16)(wr[kk * 32 + i] * gsc[ga]);
      Bf[ga][kk] = b;
    }
  }
  const float b2 = bhh[2 * Hn + j] * (2.0f * LOG2E);
  const f4 BH2 = {b2, b2, b2, b2};
  const f4 Z4 = {0.f, 0.f, 0.f, 0.f};

  __syncthreads();  // tokT + hfrag zeros visible

  // loop-invariant LDS byte addresses
  const int aadr = (lg * 256 + lr * 16) ^ ((lg & 1) << 5);
  const int wmask = ((j >> 3) & 1) << 5;
  const int wbase = (j >> 3) * 256 + (j & 7) * 2 + lg * 64;
  const int wadr0 = (wbase + (2 * hf + 0) * 16) ^ wmask;
  const int wadr1 = (wbase + (2 * hf + 1) * 16) ^ wmask;
  const int tadr = lg * 16 + hf * 8;  // ds_read_b64: tokens for rows m0,m0+1 (+ t*64)
  const int jb = j * 8;               // byte offset within table row (f16 x4)

  // prologue: tokens(0) -> xc loads; tokens(1) -> tkB
  int2 tkA = *(const int2*)((const char*)tokT + tadr);
  h4 xc0, xc1, xn0, xn1;
  xc0 = *(const h4*)(tab + tkA.x + jb);
  xc1 = *(const h4*)(tab + tkA.y + jb);
  int2 tkB = *(const int2*)((const char*)tokT + 64 + tadr);

  f16 h0 = (f16)0.f, h1 = (f16)0.f;
  const f16 ONE = (f16)1.f;
  const f16 TWO = (f16)2.f;

#define GATE(HV, CV, WA, ARv, AZv, ANH)                                        \
  {                                                                            \
    h2 arz = pkrtz(ARv, AZv);                                                  \
    h2 srz = {CV[0], CV[1]};                                                   \
    h2 t = srz + arz;                                                          \
    h2 e = {hexp2(t[0]), hexp2(t[1])};                                         \
    h2 d = e + (h2){ONE, ONE};                                                 \
    const f16 rg = hrcp(d[0]);                                                 \
    const f16 zg = hrcp(d[1]);                                                 \
    const f16 ng = ONE - TWO * hrcp(ONE + hexp2(rg * ANH + CV[2]));            \
    HV = zg * (HV - ng) + ng;                                                  \
    *(f16*)(hw + WA) = HV;                                                     \
  }

#define GRU_BODY(T, P, C0, C1, N0, N1, TKc, TKn)                               \
  {                                                                            \
    const char* hb = (const char*)hfrag + (P) * 4096;                          \
    h8 A0 = *(const h8*)(hb + aadr + 0 * 1024);                                \
    h8 A1 = *(const h8*)(hb + aadr + 1 * 1024);                                \
    h8 A2 = *(const h8*)(hb + aadr + 2 * 1024);                                \
    h8 A3 = *(const h8*)(hb + aadr + 3 * 1024);                                \
    N0 = *(const h4*)(tab + TKc.x + jb);                                       \
    N1 = *(const h4*)(tab + TKc.y + jb);                                       \
    {                                                                          \
      const int tt = ((T) + 2 < Tn) ? ((T) + 2) : (Tn - 1);                    \
      TKn = *(const int2*)((const char*)tokT + tt * 64 + tadr);                \
    }                                                                          \
    f4 aR = __builtin_amdgcn_mfma_f32_16x16x32_f16(A0, Bf[0][0], Z4, 0, 0, 0); \
    f4 aZ = __builtin_amdgcn_mfma_f32_16x16x32_f16(A0, Bf[1][0], Z4, 0, 0, 0); \
    f4 aN = __builtin_amdgcn_mfma_f32_16x16x32_f16(A0, Bf[2][0], BH2, 0, 0, 0);\
    aR = __builtin_amdgcn_mfma_f32_16x16x32_f16(A1, Bf[0][1], aR, 0, 0, 0);    \
    aZ = __builtin_amdgcn_mfma_f32_16x16x32_f16(A1, Bf[1][1], aZ, 0, 0, 0);    \
    aN = __builtin_amdgcn_mfma_f32_16x16x32_f16(A1, Bf[2][1], aN, 0, 0, 0);    \
    aR = __builtin_amdgcn_mfma_f32_16x16x32_f16(A2, Bf[0][2], aR, 0, 0, 0);    \
    aZ = __builtin_amdgcn_mfma_f32_16x16x32_f16(A2, Bf[1][2], aZ, 0, 0, 0);    \
    aN = __builtin_amdgcn_mfma_f32_16x16x32_f16(A2, Bf[2][2], aN, 0, 0, 0);    \
    aR = __builtin_amdgcn_mfma_f32_16x16x32_f16(A3, Bf[0][3], aR, 0, 0, 0);    \
    aZ = __builtin_amdgcn_mfma_f32_16x16x32_f16(A3, Bf[1][3], aZ, 0, 0, 0);    \
    aN = __builtin_amdgcn_mfma_f32_16x16x32_f16(A3, Bf[2][3], aN, 0, 0, 0);    \
    char* hw = (char*)hfrag + ((P) ^ 1) * 4096;                                \
    if (hf) {                                                                  \
      h2 an = pkrtz(aN[2], aN[3]);                                             \
      GATE(h0, C0, wadr0, aR[2], aZ[2], an[0])                                 \
      GATE(h1, C1, wadr1, aR[3], aZ[3], an[1])                                 \
    } else {                                                                   \
      h2 an = pkrtz(aN[0], aN[1]);                                             \
      GATE(h0, C0, wadr0, aR[0], aZ[0], an[0])                                 \
      GATE(h1, C1, wadr1, aR[1], aZ[1], an[1])                                 \
    }                                                                          \
    asm volatile("s_waitcnt lgkmcnt(0)\n\ts_barrier" ::: "memory");            \
  }

#pragma unroll 1
  for (int t = 0; t < Tn; t += 2) {
    GRU_BODY(t, 0, xc0, xc1, xn0, xn1, tkB, tkA)
    GRU_BODY(t + 1, 1, xn0, xn1, xc0, xc1, tkA, tkB)
  }
#undef GRU_BODY
#undef GATE

  feat[(b0 + lg * 4 + 2 * hf + 0) * En + dir * Hn + j] = (float)h0;
  feat[(b0 + lg * 4 + 2 * hf + 1) * En + dir * Hn + j] = (float)h1;
}

// ---------------- Kernel 3: adapter + LN + proj (f16 weights, dot2) ----------------
__launch_bounds__(256, 2)
__global__ void epi_k(const float* __restrict__ feat,
                      const int* __restrict__ lang_ids,
                      const f16* __restrict__ dwh,
                      const float* __restrict__ down_b,
                      const f16* __restrict__ uwh,
                      const float* __restrict__ up_b,
                      const float* __restrict__ ln_g,
                      const float* __restrict__ ln_b,
                      const f16* __restrict__ pwh,
                      const float* __restrict__ proj_b,
                      float* __restrict__ out) {
  const int tid = threadIdx.x;
  const int wv = tid >> 6, ln = tid & 63;
  const int b0 = blockIdx.x * 8;

  __shared__ f16 fl16[8][En];
  __shared__ f16 yA[16][En + 8];  // rows 8-15 uninitialized: feed only discarded C rows

#pragma unroll
  for (int s = 0; s < 8; ++s) fl16[s][tid] = (f16)feat[(b0 + s) * En + tid];
  __syncthreads();

#pragma unroll 1
  for (int si = 0; si < 2; ++si) {
    const int s = wv * 2 + si;
    const int lang = lang_ids[b0 + s];

    const int d = ln & 31, hf = ln >> 5;
    const h8* dw8 = (const h8*)(dwh + (lang * BNn + d) * En + hf * 128);
    const h8* fs8 = (const h8*)&fl16[s][hf * 128];
    float pacc = 0.f;
#pragma unroll
    for (int q = 0; q < 16; ++q) {
      h8 a = fs8[q], w = dw8[q];
#pragma unroll
      for (int p = 0; p < 4; ++p)
        pacc = dot2((h2){a[2 * p], a[2 * p + 1]}, (h2){w[2 * p], w[2 * p + 1]}, pacc);
    }
    pacc += __shfl_xor(pacc, 32);
    const float hv = pacc + down_b[lang * BNn + d];
    const float hid = 0.5f * hv * (1.0f + erff(hv * 0.70710678118f));

    h2 hp[16];
#pragma unroll
    for (int p = 0; p < 16; ++p)
      hp[p] = pkrtz(__shfl(hid, 2 * p), __shfl(hid, 2 * p + 1));

    const int e0 = ln * 4;
    float x[4];
    float s1 = 0.f, s2 = 0.f;
#pragma unroll
    for (int i = 0; i < 4; ++i) {
      const h8* uw8 = (const h8*)(uwh + (lang * En + e0 + i) * BNn);
      float a = 0.f;
#pragma unroll
      for (int q = 0; q < 4; ++q) {
        h8 u = uw8[q];
#pragma unroll
        for (int p = 0; p < 4; ++p)
          a = dot2(hp[4 * q + p], (h2){u[2 * p], u[2 * p + 1]}, a);
      }
      x[i] = a + (float)fl16[s][e0 + i] + up_b[lang * En + e0 + i];
      s1 += x[i];
      s2 = fmaf(x[i], x[i], s2);
    }
#pragma unroll
    for (int off = 32; off >= 1; off >>= 1) {
      s1 += __shfl_xor(s1, off);
      s2 += __shfl_xor(s2, off);
    }
    const float mu = s1 * (1.0f / En);
    const float var = s2 * (1.0f / En) - mu * mu;
    const float rs = rsqrtf(var + 1e-5f);
#pragma unroll
    for (int i = 0; i < 4; ++i) {
      const float yv = (x[i] - mu) * rs * ln_g[lang * En + e0 + i] + ln_b[lang * En + e0 + i];
      yA[s][e0 + i] = (f16)yv;
    }
  }
  __syncthreads();

  const int lr = ln & 15, lg = ln >> 4;
  f4 acc[4];
#pragma unroll
  for (int tt = 0; tt < 4; ++tt) {
    const float pb = proj_b[wv * 64 + tt * 16 + lr];
    acc[tt] = (f4){pb, pb, pb, pb};
  }
#pragma unroll
  for (int kk = 0; kk < 8; ++kk) {
    h8 aF = *(const h8*)(&yA[lr][kk * 32 + lg * 8]);
#pragma unroll
    for (int tt = 0; tt < 4; ++tt) {
      const int o0 = wv * 64 + tt * 16;
      h8 bF = *(const h8*)(pwh + (o0 + lr) * En + kk * 32 + lg * 8);
      acc[tt] = __builtin_amdgcn_mfma_f32_16x16x32_f16(aF, bF, acc[tt], 0, 0, 0);
    }
  }
  if (lg < 2) {
#pragma unroll
    for (int tt = 0; tt < 4; ++tt) {
      const int o0 = wv * 64 + tt * 16;
#pragma unroll
      for (int r = 0; r < 4; ++r)
        out[(b0 + lg * 4 + r) * On + o0 + lr] = acc[tt][r];
    }
  }
}

extern "C" void kernel_launch(void* const* d_in, const int* in_sizes, int n_in,
                              void* d_out, int out_size, void* d_ws, size_t ws_size,
                              hipStream_t stream) {
  const int* tokens = (const int*)d_in[0];
  const int* lang_ids = (const int*)d_in[1];
  const float* emb = (const float*)d_in[2];
  const float* w_ih_f = (const float*)d_in[3];
  const float* w_hh_f = (const float*)d_in[4];
  const float* b_ih_f = (const float*)d_in[5];
  const float* b_hh_f = (const float*)d_in[6];
  const float* w_ih_b = (const float*)d_in[7];
  const float* w_hh_b = (const float*)d_in[8];
  const float* b_ih_b = (const float*)d_in[9];
  const float* b_hh_b = (const float*)d_in[10];
  const float* down_w = (const float*)d_in[11];
  const float* down_b = (const float*)d_in[12];
  const float* up_w = (const float*)d_in[13];
  const float* up_b = (const float*)d_in[14];
  const float* ln_g = (const float*)d_in[15];
  const float* ln_b = (const float*)d_in[16];
  const float* proj_w = (const float*)d_in[17];
  const float* proj_b = (const float*)d_in[18];

  char* ws = (char*)d_ws;
  f16* xt = (f16*)ws;                              // [2][256][128][4] f16 = 512KB
  float* feat = (float*)(ws + 524288);             // [2048][256] f32 = 2MB
  f16* pwh = (f16*)(ws + 2621440);                 // [256][256] f16 = 128KB
  f16* dwh = (f16*)(ws + 2752512);                 // [3][32][256] f16 = 48KB
  f16* uwh = (f16*)(ws + 2801664);                 // [3][256][32] f16 = 48KB

  build_table_k<<<dim3(512), dim3(128), 0, stream>>>(emb, w_ih_f, b_ih_f, b_hh_f,
                                                     w_ih_b, b_ih_b, b_hh_b, xt);
  cvt_k<<<dim3(112), dim3(256), 0, stream>>>(proj_w, down_w, up_w, pwh, dwh, uwh);
  gru_k<<<dim3(256), dim3(1024), 0, stream>>>(tokens, w_hh_f, b_hh_f, w_hh_b, b_hh_b, xt, feat);
  epi_k<<<dim3(256), dim3(256), 0, stream>>>(feat, lang_ids, dwh, down_b, uwh, up_b,
                                             ln_g, ln_b, pwh, proj_b, (float*)d_out);
}

// Round 14
// 117.089 us; speedup vs baseline: 1.2085x; 1.2085x over previous
//
#include <hip/hip_runtime.h>
#include <hip/hip_bf16.h>
#include <hip/hip_fp16.h>

#define Bn 2048
#define Tn 128
#define Vn 256
#define Cn 32
#define Hn 128
#define En 256
#define On 256
#define Gn 384
#define BNn 32

typedef _Float16 f16;
typedef __attribute__((ext_vector_type(8))) _Float16 h8;
typedef __attribute__((ext_vector_type(4))) _Float16 h4;
typedef __attribute__((ext_vector_type(2))) _Float16 h2;
typedef __attribute__((ext_vector_type(2))) __fp16 hb2;
typedef __attribute__((ext_vector_type(4))) float f4;

#define LOG2E 1.4426950408889634f

__device__ __forceinline__ f16 hexp2(f16 x) {
  f16 r;
  asm("v_exp_f16 %0, %1" : "=v"(r) : "v"(x));
  return r;
}
__device__ __forceinline__ f16 hrcp(f16 x) {
  f16 r;
  asm("v_rcp_f16 %0, %1" : "=v"(r) : "v"(x));
  return r;
}
__device__ __forceinline__ h2 pkrtz(float a, float b) {
  return __builtin_bit_cast(h2, __builtin_amdgcn_cvt_pkrtz(a, b));
}
__device__ __forceinline__ float dot2(h2 a, h2 b, float c) {
#if __has_builtin(__builtin_amdgcn_fdot2)
  return __builtin_amdgcn_fdot2(__builtin_bit_cast(hb2, a), __builtin_bit_cast(hb2, b), c, false);
#else
  return fmaf((float)a[0], (float)b[0], fmaf((float)a[1], (float)b[1], c));
#endif
}

// ---------------- Kernel 1: table build + weight cvt (merged) ----------------
// blocks 0..255: xp table, 2 vocab rows per block (256 threads).
//   xt[dir][v][j][4] = { -log2e*(xr+bir+bhhr), -log2e*(xz+biz+bhhz), 2log2e*(xn+bin), 0 }
// blocks 256..367: f32->f16 weight conversion (proj_w, down_w, up_w).
__global__ void prep_k(const float* __restrict__ emb,
                       const float* __restrict__ wf,
                       const float* __restrict__ bif,
                       const float* __restrict__ bhf,
                       const float* __restrict__ wb,
                       const float* __restrict__ bib,
                       const float* __restrict__ bhb,
                       f16* __restrict__ xt,
                       const float* __restrict__ pw,
                       const float* __restrict__ dw,
                       const float* __restrict__ uw,
                       f16* __restrict__ pwh,
                       f16* __restrict__ dwh,
                       f16* __restrict__ uwh) {
  const int bid = blockIdx.x;
  const int tid = threadIdx.x;
  if (bid < 256) {
    const int vd = bid * 2 + (tid >> 7);  // 0..511: dir*256+v flattened
    const int dir = vd >> 8;
    const int v = vd & 255;
    const int j = tid & 127;
    const float* w = dir ? wb : wf;
    const float* bi = dir ? bib : bif;
    const float* bh = dir ? bhb : bhf;
    const float sc[3] = {-LOG2E, -LOG2E, 2.0f * LOG2E};
    h4 o;
    o[3] = (f16)0.f;
#pragma unroll
    for (int ga = 0; ga < 3; ++ga) {
      const int g = ga * Hn + j;
      float acc = bi[g] + (ga < 2 ? bh[g] : 0.f);
      const f4* wr = (const f4*)(w + g * Cn);
      const f4* er = (const f4*)(emb + v * Cn);
#pragma unroll
      for (int q = 0; q < 8; ++q) {
        f4 wv = wr[q], ev = er[q];
        acc = fmaf(ev.x, wv.x, acc);
        acc = fmaf(ev.y, wv.y, acc);
        acc = fmaf(ev.z, wv.z, acc);
        acc = fmaf(ev.w, wv.w, acc);
      }
      o[ga] = (f16)(acc * sc[ga]);
    }
    *(h4*)&xt[((dir * Vn + v) * Hn + j) * 4] = o;
  } else {
    const int i = ((bid - 256) * 256 + tid) * 4;
    if (i < 65536) {
      f4 v = *(const f4*)(pw + i);
      h4 o = {(f16)v.x, (f16)v.y, (f16)v.z, (f16)v.w};
      *(h4*)(pwh + i) = o;
    } else {
      const int k = i - 65536;
      if (k < 3 * BNn * En) {
        f4 v = *(const f4*)(dw + k);
        h4 o = {(f16)v.x, (f16)v.y, (f16)v.z, (f16)v.w};
        *(h4*)(dwh + k) = o;
        f4 u = *(const f4*)(uw + k);
        h4 p = {(f16)u.x, (f16)u.y, (f16)u.z, (f16)u.w};
        *(h4*)(uwh + k) = p;
      }
    }
  }
}

// ---------------- Kernel 2: bidirectional GRU (frozen at R10/R12 best) ----------------
// 256 blocks: dir = bi&1, 16 samples, 8 waves x 16 j. h fragment-major
// (byte(k,m) = (k>>3)*256 + m*16 + (k&7)*2) XOR-32 swizzled, double-buffered.
// A-frag reads first-after-barrier; xp (f16x4) + tokens (preshifted) one step
// ahead; barrier drains lgkmcnt only. Gates in packed f16.
__launch_bounds__(512, 2)
__global__ void gru_k(const int* __restrict__ tokens,
                      const float* __restrict__ whhf,
                      const float* __restrict__ bhhf,
                      const float* __restrict__ whhb,
                      const float* __restrict__ bhhb,
                      const f16* __restrict__ xt,
                      float* __restrict__ feat) {
  const int dir = blockIdx.x & 1;
  const int b0 = (blockIdx.x >> 1) * 16;
  const int tid = threadIdx.x;
  const int wv = tid >> 6;
  const int ln = tid & 63;
  const int lr = ln & 15;
  const int lg = ln >> 4;
  const int j = wv * 16 + lr;

  __shared__ f16 hfrag[2 * 2048];  // 2 x 4KB, XOR-32 swizzled
  __shared__ int tokT[Tn * 16];    // [t][s], direction-adjusted, value = tok<<10

  for (int i = tid; i < Tn * 16; i += 512) {
    const int t = i >> 4, s = i & 15;
    tokT[i] = tokens[(b0 + s) * Tn + (dir ? (Tn - 1 - t) : t)] << 10;
  }
  for (int i = tid; i < 2 * 2048; i += 512) hfrag[i] = (f16)0.f;

  const float* whh = dir ? whhb : whhf;
  const float* bhh = dir ? bhhb : bhhf;
  const char* tab = (const char*)(xt + dir * (Vn * Hn * 4));

  const float gsc[3] = {-LOG2E, -LOG2E, 2.0f * LOG2E};
  h8 Bf[3][4];
#pragma unroll
  for (int ga = 0; ga < 3; ++ga) {
    const float* wr = whh + (ga * Hn + j) * Hn + lg * 8;
#pragma unroll
    for (int kk = 0; kk < 4; ++kk) {
      h8 b;
#pragma unroll
      for (int i = 0; i < 8; ++i) b[i] = (f16)(wr[kk * 32 + i] * gsc[ga]);
      Bf[ga][kk] = b;
    }
  }
  const float b2 = bhh[2 * Hn + j] * (2.0f * LOG2E);
  const f4 BH2 = {b2, b2, b2, b2};
  const f4 Z4 = {0.f, 0.f, 0.f, 0.f};

  __syncthreads();

  const int aadr = (lg * 256 + lr * 16) ^ ((lg & 1) << 5);
  int wadr[4];
  {
    const int wmask = ((j >> 3) & 1) << 5;
    const int wbase = (j >> 3) * 256 + (j & 7) * 2 + lg * 64;
#pragma unroll
    for (int r = 0; r < 4; ++r) wadr[r] = (wbase + r * 16) ^ wmask;
  }
  const int tadr = lg * 16;
  const int jb = j * 8;

  int4 tkA = *(const int4*)((const char*)tokT + tadr);
  h4 xc0, xc1, xc2, xc3, xn0, xn1, xn2, xn3;
  xc0 = *(const h4*)(tab + tkA.x + jb);
  xc1 = *(const h4*)(tab + tkA.y + jb);
  xc2 = *(const h4*)(tab + tkA.z + jb);
  xc3 = *(const h4*)(tab + tkA.w + jb);
  int4 tkB = *(const int4*)((const char*)tokT + 64 + tadr);

  f16 h0 = (f16)0.f, h1 = (f16)0.f, h2v = (f16)0.f, h3 = (f16)0.f;
  const f16 ONE = (f16)1.f;
  const f16 TWO = (f16)2.f;

#define GATE(HV, CV, I, ANH)                                                   \
  {                                                                            \
    h2 arz = pkrtz(aR[I], aZ[I]);                                              \
    h2 srz = {CV[0], CV[1]};                                                   \
    h2 t = srz + arz;                                                          \
    h2 e = {hexp2(t[0]), hexp2(t[1])};                                         \
    h2 d = e + (h2){ONE, ONE};                                                 \
    const f16 rg = hrcp(d[0]);                                                 \
    const f16 zg = hrcp(d[1]);                                                 \
    const f16 ng = ONE - TWO * hrcp(ONE + hexp2(rg * ANH + CV[2]));            \
    HV = zg * (HV - ng) + ng;                                                  \
    *(f16*)(hw + wadr[I]) = HV;                                                \
  }

#define GRU_BODY(T, P, C0, C1, C2, C3, N0, N1, N2, N3, TKc, TKn)               \
  {                                                                            \
    const char* hb = (const char*)hfrag + (P) * 4096;                          \
    h8 A0 = *(const h8*)(hb + aadr + 0 * 1024);                                \
    h8 A1 = *(const h8*)(hb + aadr + 1 * 1024);                                \
    h8 A2 = *(const h8*)(hb + aadr + 2 * 1024);                                \
    h8 A3 = *(const h8*)(hb + aadr + 3 * 1024);                                \
    N0 = *(const h4*)(tab + TKc.x + jb);                                       \
    N1 = *(const h4*)(tab + TKc.y + jb);                                       \
    N2 = *(const h4*)(tab + TKc.z + jb);                                       \
    N3 = *(const h4*)(tab + TKc.w + jb);                                       \
    {                                                                          \
      const int tt = ((T) + 2 < Tn) ? ((T) + 2) : (Tn - 1);                    \
      TKn = *(const int4*)((const char*)tokT + tt * 64 + tadr);                \
    }                                                                          \
    f4 aR = __builtin_amdgcn_mfma_f32_16x16x32_f16(A0, Bf[0][0], Z4, 0, 0, 0); \
    f4 aZ = __builtin_amdgcn_mfma_f32_16x16x32_f16(A0, Bf[1][0], Z4, 0, 0, 0); \
    f4 aN = __builtin_amdgcn_mfma_f32_16x16x32_f16(A0, Bf[2][0], BH2, 0, 0, 0);\
    aR = __builtin_amdgcn_mfma_f32_16x16x32_f16(A1, Bf[0][1], aR, 0, 0, 0);    \
    aZ = __builtin_amdgcn_mfma_f32_16x16x32_f16(A1, Bf[1][1], aZ, 0, 0, 0);    \
    aN = __builtin_amdgcn_mfma_f32_16x16x32_f16(A1, Bf[2][1], aN, 0, 0, 0);    \
    aR = __builtin_amdgcn_mfma_f32_16x16x32_f16(A2, Bf[0][2], aR, 0, 0, 0);    \
    aZ = __builtin_amdgcn_mfma_f32_16x16x32_f16(A2, Bf[1][2], aZ, 0, 0, 0);    \
    aN = __builtin_amdgcn_mfma_f32_16x16x32_f16(A2, Bf[2][2], aN, 0, 0, 0);    \
    aR = __builtin_amdgcn_mfma_f32_16x16x32_f16(A3, Bf[0][3], aR, 0, 0, 0);    \
    aZ = __builtin_amdgcn_mfma_f32_16x16x32_f16(A3, Bf[1][3], aZ, 0, 0, 0);    \
    aN = __builtin_amdgcn_mfma_f32_16x16x32_f16(A3, Bf[2][3], aN, 0, 0, 0);    \
    char* hw = (char*)hfrag + ((P) ^ 1) * 4096;                                \
    h2 an01 = pkrtz(aN[0], aN[1]);                                             \
    h2 an23 = pkrtz(aN[2], aN[3]);                                             \
    GATE(h0, C0, 0, an01[0])                                                   \
    GATE(h1, C1, 1, an01[1])                                                   \
    GATE(h2v, C2, 2, an23[0])                                                  \
    GATE(h3, C3, 3, an23[1])                                                   \
    asm volatile("s_waitcnt lgkmcnt(0)\n\ts_barrier" ::: "memory");            \
  }

#pragma unroll 1
  for (int t = 0; t < Tn; t += 2) {
    GRU_BODY(t, 0, xc0, xc1, xc2, xc3, xn0, xn1, xn2, xn3, tkB, tkA)
    GRU_BODY(t + 1, 1, xn0, xn1, xn2, xn3, xc0, xc1, xc2, xc3, tkA, tkB)
  }
#undef GRU_BODY
#undef GATE

  feat[(b0 + lg * 4 + 0) * En + dir * Hn + j] = (float)h0;
  feat[(b0 + lg * 4 + 1) * En + dir * Hn + j] = (float)h1;
  feat[(b0 + lg * 4 + 2) * En + dir * Hn + j] = (float)h2v;
  feat[(b0 + lg * 4 + 3) * En + dir * Hn + j] = (float)h3;
}

// ---------------- Kernel 3: adapter + LN + proj (f16 weights, dot2) ----------------
__launch_bounds__(256, 2)
__global__ void epi_k(const float* __restrict__ feat,
                      const int* __restrict__ lang_ids,
                      const f16* __restrict__ dwh,
                      const float* __restrict__ down_b,
                      const f16* __restrict__ uwh,
                      const float* __restrict__ up_b,
                      const float* __restrict__ ln_g,
                      const float* __restrict__ ln_b,
                      const f16* __restrict__ pwh,
                      const float* __restrict__ proj_b,
                      float* __restrict__ out) {
  const int tid = threadIdx.x;
  const int wv = tid >> 6, ln = tid & 63;
  const int b0 = blockIdx.x * 8;

  __shared__ f16 fl16[8][En];
  __shared__ f16 yA[16][En + 8];  // rows 8-15 uninitialized: feed only discarded C rows

#pragma unroll
  for (int s = 0; s < 8; ++s) fl16[s][tid] = (f16)feat[(b0 + s) * En + tid];
  __syncthreads();

#pragma unroll 1
  for (int si = 0; si < 2; ++si) {
    const int s = wv * 2 + si;
    const int lang = lang_ids[b0 + s];

    const int d = ln & 31, hf = ln >> 5;
    const h8* dw8 = (const h8*)(dwh + (lang * BNn + d) * En + hf * 128);
    const h8* fs8 = (const h8*)&fl16[s][hf * 128];
    float pacc = 0.f;
#pragma unroll
    for (int q = 0; q < 16; ++q) {
      h8 a = fs8[q], w = dw8[q];
#pragma unroll
      for (int p = 0; p < 4; ++p)
        pacc = dot2((h2){a[2 * p], a[2 * p + 1]}, (h2){w[2 * p], w[2 * p + 1]}, pacc);
    }
    pacc += __shfl_xor(pacc, 32);
    const float hv = pacc + down_b[lang * BNn + d];
    const float hid = 0.5f * hv * (1.0f + erff(hv * 0.70710678118f));

    h2 hp[16];
#pragma unroll
    for (int p = 0; p < 16; ++p)
      hp[p] = pkrtz(__shfl(hid, 2 * p), __shfl(hid, 2 * p + 1));

    const int e0 = ln * 4;
    float x[4];
    float s1 = 0.f, s2 = 0.f;
#pragma unroll
    for (int i = 0; i < 4; ++i) {
      const h8* uw8 = (const h8*)(uwh + (lang * En + e0 + i) * BNn);
      float a = 0.f;
#pragma unroll
      for (int q = 0; q < 4; ++q) {
        h8 u = uw8[q];
#pragma unroll
        for (int p = 0; p < 4; ++p)
          a = dot2(hp[4 * q + p], (h2){u[2 * p], u[2 * p + 1]}, a);
      }
      x[i] = a + (float)fl16[s][e0 + i] + up_b[lang * En + e0 + i];
      s1 += x[i];
      s2 = fmaf(x[i], x[i], s2);
    }
#pragma unroll
    for (int off = 32; off >= 1; off >>= 1) {
      s1 += __shfl_xor(s1, off);
      s2 += __shfl_xor(s2, off);
    }
    const float mu = s1 * (1.0f / En);
    const float var = s2 * (1.0f / En) - mu * mu;
    const float rs = rsqrtf(var + 1e-5f);
#pragma unroll
    for (int i = 0; i < 4; ++i) {
      const float yv = (x[i] - mu) * rs * ln_g[lang * En + e0 + i] + ln_b[lang * En + e0 + i];
      yA[s][e0 + i] = (f16)yv;
    }
  }
  __syncthreads();

  const int lr = ln & 15, lg = ln >> 4;
  f4 acc[4];
#pragma unroll
  for (int tt = 0; tt < 4; ++tt) {
    const float pb = proj_b[wv * 64 + tt * 16 + lr];
    acc[tt] = (f4){pb, pb, pb, pb};
  }
#pragma unroll
  for (int kk = 0; kk < 8; ++kk) {
    h8 aF = *(const h8*)(&yA[lr][kk * 32 + lg * 8]);
#pragma unroll
    for (int tt = 0; tt < 4; ++tt) {
      const int o0 = wv * 64 + tt * 16;
      h8 bF = *(const h8*)(pwh + (o0 + lr) * En + kk * 32 + lg * 8);
      acc[tt] = __builtin_amdgcn_mfma_f32_16x16x32_f16(aF, bF, acc[tt], 0, 0, 0);
    }
  }
  if (lg < 2) {
#pragma unroll
    for (int tt = 0; tt < 4; ++tt) {
      const int o0 = wv * 64 + tt * 16;
#pragma unroll
      for (int r = 0; r < 4; ++r)
        out[(b0 + lg * 4 + r) * On + o0 + lr] = acc[tt][r];
    }
  }
}

extern "C" void kernel_launch(void* const* d_in, const int* in_sizes, int n_in,
                              void* d_out, int out_size, void* d_ws, size_t ws_size,
                              hipStream_t stream) {
  const int* tokens = (const int*)d_in[0];
  const int* lang_ids = (const int*)d_in[1];
  const float* emb = (const float*)d_in[2];
  const float* w_ih_f = (const float*)d_in[3];
  const float* w_hh_f = (const float*)d_in[4];
  const float* b_ih_f = (const float*)d_in[5];
  const float* b_hh_f = (const float*)d_in[6];
  const float* w_ih_b = (const float*)d_in[7];
  const float* w_hh_b = (const float*)d_in[8];
  const float* b_ih_b = (const float*)d_in[9];
  const float* b_hh_b = (const float*)d_in[10];
  const float* down_w = (const float*)d_in[11];
  const float* down_b = (const float*)d_in[12];
  const float* up_w = (const float*)d_in[13];
  const float* up_b = (const float*)d_in[14];
  const float* ln_g = (const float*)d_in[15];
  const float* ln_b = (const float*)d_in[16];
  const float* proj_w = (const float*)d_in[17];
  const float* proj_b = (const float*)d_in[18];

  char* ws = (char*)d_ws;
  f16* xt = (f16*)ws;                              // [2][256][128][4] f16 = 512KB
  float* feat = (float*)(ws + 524288);             // [2048][256] f32 = 2MB
  f16* pwh = (f16*)(ws + 2621440);                 // [256][256] f16 = 128KB
  f16* dwh = (f16*)(ws + 2752512);                 // [3][32][256] f16 = 48KB
  f16* uwh = (f16*)(ws + 2801664);                 // [3][256][32] f16 = 48KB

  prep_k<<<dim3(368), dim3(256), 0, stream>>>(emb, w_ih_f, b_ih_f, b_hh_f,
                                              w_ih_b, b_ih_b, b_hh_b, xt,
                                              proj_w, down_w, up_w, pwh, dwh, uwh);
  gru_k<<<dim3(256), dim3(512), 0, stream>>>(tokens, w_hh_f, b_hh_f, w_hh_b, b_hh_b, xt, feat);
  epi_k<<<dim3(256), dim3(256), 0, stream>>>(feat, lang_ids, dwh, down_b, uwh, up_b,
                                             ln_g, ln_b, pwh, proj_b, (float*)d_out);
}